// Round 1
// baseline (505.886 us; speedup 1.0000x reference)
//
#include <hip/hip_runtime.h>
#include <math.h>

// ---------------------------------------------------------------------------
// Stage 1: conv1(5x5,pad1) + ReLU + BN(eval) + maxpool(3,2,1, zero-pad)
//   in : x [512,3,128,128]   out: out1 [512,5,63,63]
//   w(o,c,ki,kj) = k1[((c*5+ki)*5+kj)*5 + o]   (reference reshape semantics)
// Each block: one sample, one 16x16 tile of pool outputs (4x4 tiles for 63x63).
// ---------------------------------------------------------------------------
__global__ __launch_bounds__(256) void conv1_pool_kernel(
    const float* __restrict__ x, const float* __restrict__ k1,
    const float* __restrict__ gamma, const float* __restrict__ beta,
    float* __restrict__ out1)
{
    const int b    = blockIdx.y;
    const int tile = blockIdx.x;          // 0..15
    const int ty = tile >> 2, tx = tile & 3;
    const int tid = threadIdx.x;

    __shared__ float sIn[3][37][39];      // stride 39 to dodge bank conflicts

    const int iy0 = 32 * ty - 2, ix0 = 32 * tx - 2;
    for (int idx = tid; idx < 3 * 37 * 37; idx += 256) {
        int c  = idx / 1369;
        int r  = idx - c * 1369;
        int ly = r / 37, lx = r - ly * 37;
        int gy = iy0 + ly, gx = ix0 + lx;
        float v = 0.f;
        if ((unsigned)gy < 128u && (unsigned)gx < 128u)
            v = x[((b * 3 + c) * 128 + gy) * 128 + gx];
        sIn[c][ly][lx] = v;
    }
    __syncthreads();

    const int lpy = tid >> 4, lpx = tid & 15;
    const int py = 16 * ty + lpy, px = 16 * tx + lpx;
    if (py >= 63 || px >= 63) return;

    const float invs = rsqrtf(1.0f + 1e-5f);
    float sc[5], bt[5];
#pragma unroll
    for (int o = 0; o < 5; ++o) { sc[o] = gamma[o] * invs; bt[o] = beta[o]; }

    float mx[5];
#pragma unroll
    for (int o = 0; o < 5; ++o) mx[o] = -1e30f;

    for (int dy = 0; dy < 3; ++dy) {
        const int cy = 2 * py - 1 + dy;            // in [-1,125]
        for (int dx = 0; dx < 3; ++dx) {
            const int cx = 2 * px - 1 + dx;
            if (cy < 0 || cx < 0) {                 // zero-padded pool position
#pragma unroll
                for (int o = 0; o < 5; ++o) mx[o] = fmaxf(mx[o], 0.f);
                continue;
            }
            float acc[5] = {0.f, 0.f, 0.f, 0.f, 0.f};
#pragma unroll
            for (int c = 0; c < 3; ++c)
#pragma unroll
                for (int ki = 0; ki < 5; ++ki)
#pragma unroll
                    for (int kj = 0; kj < 5; ++kj) {
                        float iv = sIn[c][2 * lpy + dy + ki][2 * lpx + dx + kj];
                        const float* w = &k1[((c * 5 + ki) * 5 + kj) * 5];
#pragma unroll
                        for (int o = 0; o < 5; ++o)
                            acc[o] = fmaf(iv, w[o], acc[o]);
                    }
#pragma unroll
            for (int o = 0; o < 5; ++o) {
                float v = fmaxf(acc[o], 0.f) * sc[o] + bt[o];  // relu -> BN
                mx[o] = fmaxf(mx[o], v);
            }
        }
    }
#pragma unroll
    for (int o = 0; o < 5; ++o)
        out1[((b * 5 + o) * 63 + py) * 63 + px] = mx[o];
}

// ---------------------------------------------------------------------------
// Stage 2: conv2(3x3,pad1) + ReLU + maxpool(3,2,1)
//   in : out1 [512,5,63,63]  out: out2 [512,9,32,32]
//   w(o,c,ki,kj) = k2[((c*3+ki)*3+kj)*9 + o]
// ---------------------------------------------------------------------------
__global__ __launch_bounds__(256) void conv2_pool_kernel(
    const float* __restrict__ in1, const float* __restrict__ k2,
    float* __restrict__ out2)
{
    const int b    = blockIdx.y;
    const int tile = blockIdx.x;          // 0..3
    const int ty = tile >> 1, tx = tile & 1;
    const int tid = threadIdx.x;

    __shared__ float sIn[5][35][37];

    const int iy0 = 32 * ty - 2, ix0 = 32 * tx - 2;
    for (int idx = tid; idx < 5 * 35 * 35; idx += 256) {
        int c  = idx / 1225;
        int r  = idx - c * 1225;
        int ly = r / 35, lx = r - ly * 35;
        int gy = iy0 + ly, gx = ix0 + lx;
        float v = 0.f;
        if ((unsigned)gy < 63u && (unsigned)gx < 63u)
            v = in1[((b * 5 + c) * 63 + gy) * 63 + gx];
        sIn[c][ly][lx] = v;
    }
    __syncthreads();

    const int lpy = tid >> 4, lpx = tid & 15;
    const int py = 16 * ty + lpy, px = 16 * tx + lpx;   // always < 32

    float mx[9];
#pragma unroll
    for (int o = 0; o < 9; ++o) mx[o] = 0.f;   // relu>=0 and zero pool-pad

    for (int dy = 0; dy < 3; ++dy) {
        const int cy = 2 * py - 1 + dy;
        if (cy < 0 || cy >= 63) continue;       // pad contributes 0 (<= mx)
        for (int dx = 0; dx < 3; ++dx) {
            const int cx = 2 * px - 1 + dx;
            if (cx < 0 || cx >= 63) continue;
            float acc[9] = {0.f,0.f,0.f,0.f,0.f,0.f,0.f,0.f,0.f};
#pragma unroll
            for (int c = 0; c < 5; ++c)
#pragma unroll
                for (int ki = 0; ki < 3; ++ki)
#pragma unroll
                    for (int kj = 0; kj < 3; ++kj) {
                        float iv = sIn[c][2 * lpy + dy + ki][2 * lpx + dx + kj];
                        const float* w = &k2[((c * 3 + ki) * 3 + kj) * 9];
#pragma unroll
                        for (int o = 0; o < 9; ++o)
                            acc[o] = fmaf(iv, w[o], acc[o]);
                    }
#pragma unroll
            for (int o = 0; o < 9; ++o) mx[o] = fmaxf(mx[o], acc[o]);
        }
    }
#pragma unroll
    for (int o = 0; o < 9; ++o)
        out2[((b * 9 + o) * 32 + py) * 32 + px] = mx[o];
}

// ---------------------------------------------------------------------------
// Stage 3: conv3(3x3,pad1) + flatten + FC(16384->6) + softmax, per sample.
//   in : out2 [512,9,32,32]   out: [512,6]
//   w(o,c,ki,kj) = k3[((c*3+ki)*3+kj)*16 + o]
//   flat index f = o*1024 + y*32 + x ; logits = flat @ fc_w.T + fc_b
// ---------------------------------------------------------------------------
__global__ __launch_bounds__(256) void conv3_fc_kernel(
    const float* __restrict__ in2, const float* __restrict__ k3,
    const float* __restrict__ fcw, const float* __restrict__ fcb,
    float* __restrict__ out)
{
    const int b   = blockIdx.x;
    const int tid = threadIdx.x;

    __shared__ float sP[9][34][36];   // zero-padded border (+1 each side in y/x)
    __shared__ float sRed[4][6];

    for (int idx = tid; idx < 9 * 34 * 36; idx += 256) {
        int c  = idx / (34 * 36);
        int r  = idx - c * (34 * 36);
        int yy = r / 36, xx = r - yy * 36;
        float v = 0.f;
        if (yy >= 1 && yy < 33 && xx >= 1 && xx < 33)
            v = in2[((b * 9 + c) * 32 + (yy - 1)) * 32 + (xx - 1)];
        sP[c][yy][xx] = v;
    }
    __syncthreads();

    float acc6[6] = {0.f,0.f,0.f,0.f,0.f,0.f};
    for (int j = 0; j < 4; ++j) {
        const int s = tid + 256 * j;          // spatial index 0..1023
        const int y = s >> 5, xc = s & 31;
        float acc16[16];
#pragma unroll
        for (int o = 0; o < 16; ++o) acc16[o] = 0.f;
#pragma unroll
        for (int c = 0; c < 9; ++c) {
            float iv[9];
#pragma unroll
            for (int ki = 0; ki < 3; ++ki)
#pragma unroll
                for (int kj = 0; kj < 3; ++kj)
                    iv[ki * 3 + kj] = sP[c][y + ki][xc + kj];
#pragma unroll
            for (int ki = 0; ki < 3; ++ki)
#pragma unroll
                for (int kj = 0; kj < 3; ++kj) {
                    float v = iv[ki * 3 + kj];
                    const float* w = &k3[((c * 3 + ki) * 3 + kj) * 16];
#pragma unroll
                    for (int o = 0; o < 16; ++o)
                        acc16[o] = fmaf(v, w[o], acc16[o]);
                }
        }
        // FC contribution of these 16 conv3 outputs (no relu after conv3)
#pragma unroll
        for (int o = 0; o < 16; ++o) {
            const int f = o * 1024 + s;
#pragma unroll
            for (int cls = 0; cls < 6; ++cls)
                acc6[cls] = fmaf(acc16[o], fcw[cls * 16384 + f], acc6[cls]);
        }
    }

    // block reduction of 6 logits
#pragma unroll
    for (int cls = 0; cls < 6; ++cls) {
        float v = acc6[cls];
#pragma unroll
        for (int off = 32; off >= 1; off >>= 1)
            v += __shfl_xor(v, off, 64);
        if ((tid & 63) == 0) sRed[tid >> 6][cls] = v;
    }
    __syncthreads();
    if (tid == 0) {
        float logits[6], mxl = -1e30f;
        for (int cls = 0; cls < 6; ++cls) {
            float l = sRed[0][cls] + sRed[1][cls] + sRed[2][cls] + sRed[3][cls]
                      + fcb[cls];
            logits[cls] = l;
            mxl = fmaxf(mxl, l);
        }
        float ssum = 0.f;
        for (int cls = 0; cls < 6; ++cls) {
            logits[cls] = expf(logits[cls] - mxl);
            ssum += logits[cls];
        }
        for (int cls = 0; cls < 6; ++cls)
            out[b * 6 + cls] = logits[cls] / ssum;
    }
}

extern "C" void kernel_launch(void* const* d_in, const int* in_sizes, int n_in,
                              void* d_out, int out_size, void* d_ws, size_t ws_size,
                              hipStream_t stream)
{
    const float* x     = (const float*)d_in[0];
    const float* k1    = (const float*)d_in[1];
    const float* gamma = (const float*)d_in[2];
    const float* beta  = (const float*)d_in[3];
    const float* k2    = (const float*)d_in[4];
    const float* k3    = (const float*)d_in[5];
    const float* fcw   = (const float*)d_in[6];
    const float* fcb   = (const float*)d_in[7];
    float* out = (float*)d_out;

    float* out1 = (float*)d_ws;                       // 512*5*63*63  (40.6 MB)
    float* out2 = out1 + (size_t)512 * 5 * 63 * 63;   // 512*9*32*32  (18.9 MB)

    conv1_pool_kernel<<<dim3(16, 512), 256, 0, stream>>>(x, k1, gamma, beta, out1);
    conv2_pool_kernel<<<dim3(4, 512), 256, 0, stream>>>(out1, k2, out2);
    conv3_fc_kernel<<<dim3(512), 256, 0, stream>>>(out2, k3, fcw, fcb, out);
}